// Round 16
// baseline (106.466 us; speedup 1.0000x reference)
//
#include <hip/hip_runtime.h>

#define B_   2
#define L_   2048
#define H_   1024
#define NH_  16
#define KVH_ 4
#define HD_  64

typedef short short8 __attribute__((ext_vector_type(8)));
typedef float f32x4 __attribute__((ext_vector_type(4)));
typedef float f32x16 __attribute__((ext_vector_type(16)));
typedef unsigned short u16x4 __attribute__((ext_vector_type(4)));
typedef unsigned int u32x4 __attribute__((ext_vector_type(4)));

#define LOG2E 1.4426950408889634f
#define QSC   0.18033688011112042f   /* 0.125 * log2(e) */
#define MFMA   __builtin_amdgcn_mfma_f32_16x16x32_bf16
#define MFMA32 __builtin_amdgcn_mfma_f32_32x32x16_bf16

#if __has_builtin(__builtin_amdgcn_exp2f)
#define EXP2(x) __builtin_amdgcn_exp2f(x)
#else
#define EXP2(x) exp2f(x)
#endif

static __device__ __forceinline__ unsigned short f2bf(float f) {
  unsigned int u = __float_as_uint(f);
  u += 0x7FFFu + ((u >> 16) & 1u);
  return (unsigned short)(u >> 16);
}

static __device__ __forceinline__ unsigned int cvtpk(float lo, float hi) {
  unsigned int r;
  asm("v_cvt_pk_bf16_f32 %0, %1, %2" : "=v"(r) : "v"(lo), "v"(hi));
  return r;
}

// dst' = {dst.lo32lanes, src.lo32lanes}, src' = {dst.hi32lanes, src.hi32lanes}
static __device__ __forceinline__ void plswap(unsigned int& a, unsigned int& b) {
  asm("v_permlane32_swap_b32 %0, %1" : "+v"(a), "+v"(b));
}

static __device__ __forceinline__ short8 mk8(unsigned int w0, unsigned int w1,
                                             unsigned int w2, unsigned int w3) {
  union { unsigned int u[4]; short8 s; } x;
  x.u[0] = w0; x.u[1] = w1; x.u[2] = w2; x.u[3] = w3;
  return x.s;
}

static __device__ __forceinline__ void gload_lds16(const void* g, void* l) {
  __builtin_amdgcn_global_load_lds(
      (const __attribute__((address_space(1))) unsigned int*)g,
      (__attribute__((address_space(3))) unsigned int*)l, 16, 0, 0);
}

template <int N> static __device__ __forceinline__ void waitcnt_vm() {
  if constexpr (N == 0)      asm volatile("s_waitcnt vmcnt(0)" ::: "memory");
  else if constexpr (N == 4) asm volatile("s_waitcnt vmcnt(4)" ::: "memory");
  else if constexpr (N == 6) asm volatile("s_waitcnt vmcnt(6)" ::: "memory");
  else if constexpr (N == 8) asm volatile("s_waitcnt vmcnt(8)" ::: "memory");
  else                       asm volatile("s_waitcnt vmcnt(0)" ::: "memory");
}

// ---------------- prep: convert weights + mask scan (x conversion fused into gemm0) ----------------
__global__ __launch_bounds__(256) void k_prep(const float* __restrict__ Wq,
                                              const float* __restrict__ Wk,
                                              const float* __restrict__ Wv,
                                              const float* __restrict__ Wo,
                                              const float* __restrict__ mask,
                                              unsigned short* __restrict__ wcat,
                                              unsigned short* __restrict__ wo_b,
                                              unsigned char* __restrict__ flags) {
  const int blk = blockIdx.x;
  const int t = threadIdx.x;
  if (blk < 2560) {                       // ---- convert weights ----
    int r = blk;
    int c = t * 4;
    const float* src;
    unsigned short* dst;
    if (r < 1024)      { src = Wq + (size_t)r * 1024;          dst = wcat + (size_t)r * 1024; }
    else if (r < 1280) { src = Wk + (size_t)(r - 1024) * 1024; dst = wcat + (size_t)r * 1024; }
    else if (r < 1536) { src = Wv + (size_t)(r - 1280) * 1024; dst = wcat + (size_t)r * 1024; }
    else               { src = Wo + (size_t)(r - 1536) * 1024; dst = wo_b + (size_t)(r - 1536) * 1024; }
    float4 v = *(const float4*)(src + c);
    u16x4 o = { f2bf(v.x), f2bf(v.y), f2bf(v.z), f2bf(v.w) };
    *(u16x4*)(dst + c) = o;
  } else {                                // ---- mask block-zero scan ----
    const int mb = blk - 2560;            // b*1024 + qb*32 + kb
    const int b = mb >> 10, qb = (mb >> 5) & 31, kb = mb & 31;
    const float* base = mask + ((size_t)b * L_ + qb * 64) * L_ + kb * 64;
    const int r0 = t >> 4, c = (t & 15) * 4;
    bool nz = false;
#pragma unroll
    for (int i = 0; i < 4; ++i) {
      float4 v = *(const float4*)(base + (size_t)(r0 + i * 16) * L_ + c);
      nz |= (v.x != 0.f) | (v.y != 0.f) | (v.z != 0.f) | (v.w != 0.f);
    }
    __shared__ int anyv;
    if (t == 0) anyv = 0;
    __syncthreads();
    if (__any(nz) && (t & 63) == 0) atomicOr(&anyv, 1);
    __syncthreads();
    if (t == 0) flags[mb] = (unsigned char)anyv;
  }
}

// ---------------- GEMM (BMx128, BK=64, XOR-swizzle, 2-phase dbuf, counted vmcnt) ----------------
// MODE 0 (BM=64): A read directly from fp32 x, reg-staged + cvt_pk->LDS (conversion fused,
//   saving the prep x round-trip). Per iter: vmcnt(4) [A(it) regs landed; B(it)'s 4 gloads
//   newer] -> WRITEA(cur) -> LOADA(it+1) -> ISSUEB(cur^1,it+1) -> vmcnt(8) [B(it) in LDS;
//   8 newest stay in flight] -> lgkm+barrier -> compute -> lgkm+barrier.
// MODE 1 (BM=128): bf16 A via global_load_lds, R15's counted-vmcnt scheme.
template <int MODE, int BM>
__global__ __launch_bounds__(256, BM == 64 ? 3 : 2)
void k_gemm(const float* __restrict__ Af,
            const unsigned short* __restrict__ Ab,
            const unsigned short* __restrict__ Bt,
            const float* __restrict__ bias0,
            const float* __restrict__ bias1,
            const float* __restrict__ bias2,
            unsigned short* __restrict__ q_ws,
            unsigned short* __restrict__ k_ws,
            unsigned short* __restrict__ vt_ws,
            float* __restrict__ outp) {
  constexpr int MR = BM / 32;             // M-frags per wave
  constexpr int ACH = BM * 8 / 256;       // A staging chunks (2 for BM=64, 4 for BM=128)
  const int bn = blockIdx.x, bm = blockIdx.y;
  const int t = threadIdx.x;
  const int lane = t & 63, li = lane & 15, g = lane >> 4;
  const int wid = t >> 6, wr = wid >> 1, wc = wid & 1;
  __shared__ unsigned short lds_a[2][BM * 64];    // [buf][row][slot], slot s = G col s^(row&7)
  __shared__ unsigned short lds_b[2][128 * 64];

  const f32x4 z = {0.f, 0.f, 0.f, 0.f};
  f32x4 acc[MR][4];
#pragma unroll
  for (int m = 0; m < MR; ++m)
#pragma unroll
    for (int n = 0; n < 4; ++n) acc[m][n] = z;

  int adst[ACH], bdst[4];
  const float* afsrc[ACH];
  const unsigned short* absrc[ACH];
  const unsigned short* bsrc[4];
#pragma unroll
  for (int c = 0; c < ACH; ++c) {
    const int idx = c * 256 + t, row = idx >> 3, sl = idx & 7;
    const int gcol = (sl ^ (row & 7)) * 8;
    if (MODE == 0) afsrc[c] = Af + (size_t)(bm * BM + row) * 1024 + gcol;
    else           absrc[c] = Ab + (size_t)(bm * BM + row) * 1024 + gcol;
    adst[c] = idx * 8;
  }
#pragma unroll
  for (int c = 0; c < 4; ++c) {
    const int idx = c * 256 + t, row = idx >> 3, sl = idx & 7;
    bsrc[c] = Bt + (size_t)(bn * 128 + row) * 1024 + ((sl ^ (row & 7)) * 8);
    bdst[c] = idx * 8;
  }
  const int rs = li & 7;

  if constexpr (MODE == 0) {
    // ---------- fused-convert A path ----------
    f32x4 ar[ACH][2];                     // fp32 A regs for the next tile
#define LOADA(kc)                                                        \
    { _Pragma("unroll")                                                  \
      for (int c = 0; c < ACH; ++c) {                                    \
        ar[c][0] = *(const f32x4*)(afsrc[c] + (kc));                     \
        ar[c][1] = *(const f32x4*)(afsrc[c] + (kc) + 4);                 \
      } }
#define WRITEA(buf)                                                      \
    { _Pragma("unroll")                                                  \
      for (int c = 0; c < ACH; ++c) {                                    \
        u32x4 w = { cvtpk(ar[c][0][0], ar[c][0][1]),                     \
                    cvtpk(ar[c][0][2], ar[c][0][3]),                     \
                    cvtpk(ar[c][1][0], ar[c][1][1]),                     \
                    cvtpk(ar[c][1][2], ar[c][1][3]) };                   \
        *(u32x4*)&lds_a[buf][adst[c]] = w;                               \
      } }
#define ISSUEB(buf, kc)                                                  \
    { _Pragma("unroll")                                                  \
      for (int c = 0; c < 4; ++c) gload_lds16(bsrc[c] + (kc), &lds_b[buf][bdst[c]]); }

    LOADA(0);                             // A(0) regs in flight
    ISSUEB(0, 0);                         // B(0) -> buf0 in flight

#pragma unroll 1
    for (int it = 0; it < 16; ++it) {
      const int cur = it & 1;
      waitcnt_vm<MODE == 0 ? 4 : 0>();    // A(it) regs landed (B(it)'s 4 gloads newer)
      __builtin_amdgcn_sched_barrier(0);
      WRITEA(cur);                        // cur's A region: last read 2 barriers ago
      if (it + 1 < 16) {
        LOADA((it + 1) * 64);             // safe: ar[] consumed by WRITEA above
        ISSUEB(cur ^ 1, (it + 1) * 64);   // cur^1 readers finished at prev end-barrier
        waitcnt_vm<8>();                  // B(it) in LDS; 8 newest stay in flight
      } else {
        waitcnt_vm<0>();
      }
      asm volatile("s_waitcnt lgkmcnt(0)" ::: "memory");  // WRITEA visible
      __builtin_amdgcn_s_barrier();
      __builtin_amdgcn_sched_barrier(0);
#pragma unroll
      for (int ks = 0; ks < 2; ++ks) {
        short8 af[MR], bf[4];
#pragma unroll
        for (int m = 0; m < MR; ++m)
          af[m] = *(const short8*)&lds_a[cur][(wr * (BM / 2) + m * 16 + li) * 64 +
                                              (((ks * 4 + g) ^ rs) * 8)];
#pragma unroll
        for (int n = 0; n < 4; ++n)
          bf[n] = *(const short8*)&lds_b[cur][(wc * 64 + n * 16 + li) * 64 +
                                              (((ks * 4 + g) ^ rs) * 8)];
#pragma unroll
        for (int m = 0; m < MR; ++m)
#pragma unroll
          for (int n = 0; n < 4; ++n)
            acc[m][n] = MFMA(af[m], bf[n], acc[m][n], 0, 0, 0);
      }
      asm volatile("s_waitcnt lgkmcnt(0)" ::: "memory");  // my reads of cur done
      __builtin_amdgcn_s_barrier();
      __builtin_amdgcn_sched_barrier(0);
    }
#undef LOADA
#undef WRITEA
#undef ISSUEB
  } else {
    // ---------- all-gload_lds path (R15) ----------
    constexpr int NLOADS = ACH + 4;
#define GSTAGE(buf, kc)                                                  \
    { _Pragma("unroll")                                                  \
      for (int c = 0; c < ACH; ++c) gload_lds16(absrc[c] + (kc), &lds_a[buf][adst[c]]); \
      _Pragma("unroll")                                                  \
      for (int c = 0; c < 4; ++c)   gload_lds16(bsrc[c] + (kc), &lds_b[buf][bdst[c]]); }

    GSTAGE(0, 0);

#pragma unroll 1
    for (int it = 0; it < 16; ++it) {
      const int cur = it & 1;
      if (it + 1 < 16) {
        GSTAGE(cur ^ 1, (it + 1) * 64);
        waitcnt_vm<NLOADS>();
      } else {
        waitcnt_vm<0>();
      }
      __builtin_amdgcn_s_barrier();
      __builtin_amdgcn_sched_barrier(0);
#pragma unroll
      for (int ks = 0; ks < 2; ++ks) {
        short8 af[MR], bf[4];
#pragma unroll
        for (int m = 0; m < MR; ++m)
          af[m] = *(const short8*)&lds_a[cur][(wr * (BM / 2) + m * 16 + li) * 64 +
                                              (((ks * 4 + g) ^ rs) * 8)];
#pragma unroll
        for (int n = 0; n < 4; ++n)
          bf[n] = *(const short8*)&lds_b[cur][(wc * 64 + n * 16 + li) * 64 +
                                              (((ks * 4 + g) ^ rs) * 8)];
#pragma unroll
        for (int m = 0; m < MR; ++m)
#pragma unroll
          for (int n = 0; n < 4; ++n)
            acc[m][n] = MFMA(af[m], bf[n], acc[m][n], 0, 0, 0);
      }
      asm volatile("s_waitcnt lgkmcnt(0)" ::: "memory");
      __builtin_amdgcn_s_barrier();
      __builtin_amdgcn_sched_barrier(0);
    }
#undef GSTAGE
  }

#pragma unroll
  for (int m = 0; m < MR; ++m) {
    const int row0 = bm * BM + wr * (BM / 2) + m * 16 + 4 * g;
#pragma unroll
    for (int n = 0; n < 4; ++n) {
      const int col = bn * 128 + wc * 64 + n * 16 + li;
      f32x4 v = acc[m][n];
      if (MODE == 1) {
        const float bias = bias0[col];
#pragma unroll
        for (int r = 0; r < 4; ++r) outp[(size_t)(row0 + r) * 1024 + col] = v[r] + bias;
      } else {
        if (col < 1024) {
          const float bias = bias0[col];
#pragma unroll
          for (int r = 0; r < 4; ++r) q_ws[(size_t)(row0 + r) * 1024 + col] = f2bf((v[r] + bias) * QSC);
        } else if (col < 1280) {
          const int cc = col - 1024;
          const float bias = bias1[cc];
#pragma unroll
          for (int r = 0; r < 4; ++r) k_ws[(size_t)(row0 + r) * 256 + cc] = f2bf(v[r] + bias);
        } else {
          const int cc = col - 1280;
          const float bias = bias2[cc];
          const int kvh = cc >> 6, d = cc & 63;
          const int b = row0 >> 11, l0 = row0 & 2047;
          u16x4 pk = { f2bf(v[0] + bias), f2bf(v[1] + bias), f2bf(v[2] + bias), f2bf(v[3] + bias) };
          *(u16x4*)(vt_ws + ((size_t)((b * KVH_ + kvh) * 64 + d)) * 2048 + l0) = pk;
        }
      }
    }
  }
}

// ---------------- flash attention (GQA, 8 waves: (kj-half, head), 32x32 MFMA, reg-P) ----------------
// Frozen R9 configuration (best measured: 48.4 us, VGPR 64, zero spill).
__global__ __launch_bounds__(512, 4) void k_attn(const unsigned short* __restrict__ q_ws,
                                                 const unsigned short* __restrict__ k_ws,
                                                 const unsigned short* __restrict__ vt_ws,
                                                 const float* __restrict__ mask,
                                                 const unsigned char* __restrict__ mflags,
                                                 unsigned short* __restrict__ ctx) {
  const int bk = blockIdx.x;            // b*4 + kvh (== XCD id -> L2 locality)
  const int qt = blockIdx.y;            // 32-row q tile
  const int b = bk >> 2, kvh = bk & 3;
  const int t = threadIdx.x;            // 0..511
  const int wid = t >> 6, lane = t & 63;
  const int l31 = lane & 31, g1 = lane >> 5;
  const int h = wid & 3, kh = wid >> 2;

  __shared__ unsigned short smem[16384];   // 32KB: 2 bufs x [K 8KB | V 8KB]
  __shared__ float lred[4][64];            // [h][lane] l partials from kh=1

  const unsigned short* qbase = q_ws + ((size_t)b * L_ + qt * 32 + l31) * H_ +
                                (kvh * 4 + h) * 64 + g1 * 8;
  short8 qf[4];
#pragma unroll
  for (int ks = 0; ks < 4; ++ks) qf[ks] = *(const short8*)(qbase + ks * 16);

  const unsigned int* fp = (const unsigned int*)(mflags + b * 1024 + (qt >> 1) * 32);
  unsigned int fm = 0;
#pragma unroll
  for (int w = 0; w < 8; ++w) {
    unsigned int wv = fp[w];
    fm |= ((wv & 0x000000FFu) ? 1u : 0u) << (w * 4 + 0);
    fm |= ((wv & 0x0000FF00u) ? 1u : 0u) << (w * 4 + 1);
    fm |= ((wv & 0x00FF0000u) ? 1u : 0u) << (w * 4 + 2);
    fm |= ((wv & 0xFF000000u) ? 1u : 0u) << (w * 4 + 3);
  }
  fm = __builtin_amdgcn_readfirstlane(fm);

  const int srow = t >> 3, sgr = t & 7;
  const int swz = (sgr ^ (srow & 7)) * 8;
  const unsigned short* ksrc = k_ws + ((size_t)b * L_ + srow) * 256 + kvh * 64 + swz;
  const unsigned short* vsrc = vt_ws + ((size_t)(b * KVH_ + kvh) * 64 + srow) * 2048 + swz;

  const f32x16 z16 = {0,0,0,0,0,0,0,0,0,0,0,0,0,0,0,0};
  f32x16 o_[2];
  o_[0] = z16; o_[1] = z16;
  float l_part = 0.f;

  const int rK = kh * 32 + l31, swK = rK & 7;
  const int swV = l31 & 7;

  short8 kst, vst;
#define LOADR(kt) { kst = *(const short8*)(ksrc + (size_t)(kt) * 16384); \
                    vst = *(const short8*)(vsrc + (kt) * 64); }
#define WRITES(buf) { unsigned short* dk = smem + (buf) * 8192;          \
                      *(short8*)(dk + t * 8) = kst;                      \
                      *(short8*)(dk + 4096 + t * 8) = vst; }

  LOADR(0);
  WRITES(0);
  LOADR(1);
  __syncthreads();

#pragma unroll 1
  for (int kt = 0; kt < 32; ++kt) {
    const int cur = kt & 1;
    const unsigned short* lk = smem + cur * 8192;
    const unsigned short* lv = lk + 4096;

    short8 kf[4];
#pragma unroll
    for (int ks = 0; ks < 4; ++ks)
      kf[ks] = *(const short8*)&lk[rK * 64 + ((ks * 2 + g1) ^ swK) * 8];
    short8 vf[2][2];
#pragma unroll
    for (int db = 0; db < 2; ++db)
#pragma unroll
      for (int s = 0; s < 2; ++s)
        vf[db][s] = *(const short8*)&lv[(db * 32 + l31) * 64 + ((kh * 4 + s * 2 + g1) ^ swV) * 8];

    asm volatile("s_waitcnt vmcnt(0)" ::: "memory");
    if (kt + 1 < 32) WRITES(cur ^ 1);
    if (kt + 2 < 32) LOADR(kt + 2);

    f32x16 sv = z16;
    __builtin_amdgcn_s_setprio(1);
#pragma unroll
    for (int ks = 0; ks < 4; ++ks) sv = MFMA32(kf[ks], qf[ks], sv, 0, 0, 0);
    __builtin_amdgcn_s_setprio(0);

    if (fm & (1u << kt)) {
      const float* mrow = mask + ((size_t)b * L_ + qt * 32 + l31) * L_ + kt * 64 + kh * 32 + g1 * 4;
#pragma unroll
      for (int rg = 0; rg < 4; ++rg) {
        float4 mv = *(const float4*)(mrow + rg * 8);
#pragma unroll
        for (int j = 0; j < 4; ++j) sv[rg * 4 + j] = fmaf((&mv.x)[j], LOG2E, sv[rg * 4 + j]);
      }
    }

    float e[16];
#pragma unroll
    for (int r = 0; r < 16; ++r) e[r] = EXP2(sv[r]);
    l_part += (((e[0] + e[1]) + (e[2] + e[3])) + ((e[4] + e[5]) + (e[6] + e[7]))) +
              (((e[8] + e[9]) + (e[10] + e[11])) + ((e[12] + e[13]) + (e[14] + e[15])));
    unsigned int w0 = cvtpk(e[0], e[1]),   w1 = cvtpk(e[2], e[3]);
    unsigned int w2 = cvtpk(e[4], e[5]),   w3 = cvtpk(e[6], e[7]);
    unsigned int w4 = cvtpk(e[8], e[9]),   w5 = cvtpk(e[10], e[11]);
    unsigned int w6 = cvtpk(e[12], e[13]), w7 = cvtpk(e[14], e[15]);
    plswap(w0, w2); plswap(w1, w3);
    plswap(w4, w6); plswap(w5, w7);
    short8 pa0 = mk8(w0, w1, w2, w3);
    short8 pa1 = mk8(w4, w5, w6, w7);

    __builtin_amdgcn_s_setprio(1);
#pragma unroll
    for (int db = 0; db < 2; ++db) {
      o_[db] = MFMA32(vf[db][0], pa0, o_[db], 0, 0, 0);
      o_[db] = MFMA32(vf[db][1], pa1, o_[db], 0, 0, 0);
    }
    __builtin_amdgcn_s_setprio(0);

    asm volatile("s_waitcnt lgkmcnt(0)" ::: "memory");
    __builtin_amdgcn_s_barrier();
    __builtin_amdgcn_sched_barrier(0);
  }
#undef LOADR
#undef WRITES

  float lt = l_part + __shfl_xor(l_part, 32);
  float* red = (float*)smem;

  if (kh == 1) {
    lred[h][lane] = lt;
#pragma unroll
    for (int db = 0; db < 2; ++db)
#pragma unroll
      for (int w4 = 0; w4 < 4; ++w4) {
        f32x4 pv = { o_[db][w4 * 4 + 0], o_[db][w4 * 4 + 1],
                     o_[db][w4 * 4 + 2], o_[db][w4 * 4 + 3] };
        *(f32x4*)&red[(((h * 2 + db) * 4 + w4) * 64 + lane) * 4] = pv;
      }
  }
  __syncthreads();

  if (kh == 0) {
    const float inv = 1.f / (lt + lred[h][lane]);
#pragma unroll
    for (int db = 0; db < 2; ++db) {
      f32x16 acc = o_[db];
#pragma unroll
      for (int w4 = 0; w4 < 4; ++w4) {
        f32x4 pv = *(const f32x4*)&red[(((h * 2 + db) * 4 + w4) * 64 + lane) * 4];
#pragma unroll
        for (int j = 0; j < 4; ++j) acc[w4 * 4 + j] += pv[j];
      }
      unsigned short* cp = ctx + ((size_t)b * L_ + qt * 32 + l31) * H_ +
                           (kvh * 4 + h) * 64 + db * 32 + g1 * 4;
#pragma unroll
      for (int k4 = 0; k4 < 4; ++k4) {
        unsigned int a0 = cvtpk(acc[4 * k4 + 0] * inv, acc[4 * k4 + 1] * inv);
        unsigned int a1 = cvtpk(acc[4 * k4 + 2] * inv, acc[4 * k4 + 3] * inv);
        *(unsigned int*)(cp + 8 * k4) = a0;
        *(unsigned int*)(cp + 8 * k4 + 2) = a1;
      }
    }
  }
}

// ---------------- launch ----------------
extern "C" void kernel_launch(void* const* d_in, const int* in_sizes, int n_in,
                              void* d_out, int out_size, void* d_ws, size_t ws_size,
                              hipStream_t stream) {
  const float* x    = (const float*)d_in[0];
  const float* mask = (const float*)d_in[1];
  const float* Wq   = (const float*)d_in[2];
  const float* bq   = (const float*)d_in[3];
  const float* Wk   = (const float*)d_in[4];
  const float* bk   = (const float*)d_in[5];
  const float* Wv   = (const float*)d_in[6];
  const float* bv   = (const float*)d_in[7];
  const float* Wo   = (const float*)d_in[8];
  const float* bo   = (const float*)d_in[9];
  float* out = (float*)d_out;

  char* ws = (char*)d_ws;
  unsigned short* ctx   = (unsigned short*)(ws);                 // 8 MB
  unsigned short* wcat  = (unsigned short*)(ws + 8388608);       // 3 MB
  unsigned short* wo_b  = (unsigned short*)(ws + 11534336);      // 2 MB
  unsigned short* q_ws  = (unsigned short*)(ws + 13631488);      // 8 MB
  unsigned short* k_ws  = (unsigned short*)(ws + 22020096);      // 2 MB
  unsigned short* vt_ws = (unsigned short*)(ws + 24117248);      // 2 MB
  unsigned char*  mflg  = (unsigned char*)(ws + 26214400);       // 2 KB

  k_prep<<<dim3(4608), dim3(256), 0, stream>>>(Wq, Wk, Wv, Wo, mask, wcat, wo_b, mflg);
  k_gemm<0, 64><<<dim3(12, 64), dim3(256), 0, stream>>>(x, nullptr, wcat, bq, bk, bv,
                                                        q_ws, k_ws, vt_ws, nullptr);
  k_attn<<<dim3(8, 64), dim3(512), 0, stream>>>(q_ws, k_ws, vt_ws, mask, mflg, ctx);
  k_gemm<1, 128><<<dim3(8, 32), dim3(256), 0, stream>>>(nullptr, ctx, wo_b, bo, nullptr,
                                                        nullptr, nullptr, nullptr, nullptr, out);
}

// Round 17
// 104.345 us; speedup vs baseline: 1.0203x; 1.0203x over previous
//
#include <hip/hip_runtime.h>

#define B_   2
#define L_   2048
#define H_   1024
#define NH_  16
#define KVH_ 4
#define HD_  64

typedef short short8 __attribute__((ext_vector_type(8)));
typedef float f32x4 __attribute__((ext_vector_type(4)));
typedef float f32x16 __attribute__((ext_vector_type(16)));
typedef unsigned short u16x4 __attribute__((ext_vector_type(4)));

#define LOG2E 1.4426950408889634f
#define QSC   0.18033688011112042f   /* 0.125 * log2(e) */
#define MFMA   __builtin_amdgcn_mfma_f32_16x16x32_bf16
#define MFMA32 __builtin_amdgcn_mfma_f32_32x32x16_bf16

#if __has_builtin(__builtin_amdgcn_exp2f)
#define EXP2(x) __builtin_amdgcn_exp2f(x)
#else
#define EXP2(x) exp2f(x)
#endif

static __device__ __forceinline__ unsigned short f2bf(float f) {
  unsigned int u = __float_as_uint(f);
  u += 0x7FFFu + ((u >> 16) & 1u);
  return (unsigned short)(u >> 16);
}

static __device__ __forceinline__ unsigned int cvtpk(float lo, float hi) {
  unsigned int r;
  asm("v_cvt_pk_bf16_f32 %0, %1, %2" : "=v"(r) : "v"(lo), "v"(hi));
  return r;
}

// dst' = {dst.lo32lanes, src.lo32lanes}, src' = {dst.hi32lanes, src.hi32lanes}
static __device__ __forceinline__ void plswap(unsigned int& a, unsigned int& b) {
  asm("v_permlane32_swap_b32 %0, %1" : "+v"(a), "+v"(b));
}

static __device__ __forceinline__ short8 mk8(unsigned int w0, unsigned int w1,
                                             unsigned int w2, unsigned int w3) {
  union { unsigned int u[4]; short8 s; } x;
  x.u[0] = w0; x.u[1] = w1; x.u[2] = w2; x.u[3] = w3;
  return x.s;
}

static __device__ __forceinline__ void gload_lds16(const void* g, void* l) {
  __builtin_amdgcn_global_load_lds(
      (const __attribute__((address_space(1))) unsigned int*)g,
      (__attribute__((address_space(3))) unsigned int*)l, 16, 0, 0);
}

// counted vmcnt wait (literal must be compile-time)
template <int N> static __device__ __forceinline__ void waitcnt_vm() {
  if constexpr (N == 0)      asm volatile("s_waitcnt vmcnt(0)" ::: "memory");
  else if constexpr (N == 6) asm volatile("s_waitcnt vmcnt(6)" ::: "memory");
  else if constexpr (N == 8) asm volatile("s_waitcnt vmcnt(8)" ::: "memory");
  else                       asm volatile("s_waitcnt vmcnt(0)" ::: "memory");
}

// ---------------- merged prep: convert x, convert weights, mask scan ----------------
__global__ __launch_bounds__(256) void k_prep(const float* __restrict__ x,
                                              const float* __restrict__ Wq,
                                              const float* __restrict__ Wk,
                                              const float* __restrict__ Wv,
                                              const float* __restrict__ Wo,
                                              const float* __restrict__ mask,
                                              unsigned short* __restrict__ xb,
                                              unsigned short* __restrict__ wcat,
                                              unsigned short* __restrict__ wo_b,
                                              unsigned char* __restrict__ flags) {
  const int blk = blockIdx.x;
  const int t = threadIdx.x;
  if (blk < 4096) {                       // ---- convert x ----
    size_t i = ((size_t)blk * 256 + t) * 4;
    float4 v = *(const float4*)(x + i);
    u16x4 o = { f2bf(v.x), f2bf(v.y), f2bf(v.z), f2bf(v.w) };
    *(u16x4*)(xb + i) = o;
  } else if (blk < 6656) {                // ---- convert weights ----
    int r = blk - 4096;
    int c = t * 4;
    const float* src;
    unsigned short* dst;
    if (r < 1024)      { src = Wq + (size_t)r * 1024;          dst = wcat + (size_t)r * 1024; }
    else if (r < 1280) { src = Wk + (size_t)(r - 1024) * 1024; dst = wcat + (size_t)r * 1024; }
    else if (r < 1536) { src = Wv + (size_t)(r - 1280) * 1024; dst = wcat + (size_t)r * 1024; }
    else               { src = Wo + (size_t)(r - 1536) * 1024; dst = wo_b + (size_t)(r - 1536) * 1024; }
    float4 v = *(const float4*)(src + c);
    u16x4 o = { f2bf(v.x), f2bf(v.y), f2bf(v.z), f2bf(v.w) };
    *(u16x4*)(dst + c) = o;
  } else {                                // ---- mask block-zero scan ----
    const int mb = blk - 6656;            // b*1024 + qb*32 + kb
    const int b = mb >> 10, qb = (mb >> 5) & 31, kb = mb & 31;
    const float* base = mask + ((size_t)b * L_ + qb * 64) * L_ + kb * 64;
    const int r0 = t >> 4, c = (t & 15) * 4;
    bool nz = false;
#pragma unroll
    for (int i = 0; i < 4; ++i) {
      float4 v = *(const float4*)(base + (size_t)(r0 + i * 16) * L_ + c);
      nz |= (v.x != 0.f) | (v.y != 0.f) | (v.z != 0.f) | (v.w != 0.f);
    }
    __shared__ int anyv;
    if (t == 0) anyv = 0;
    __syncthreads();
    if (__any(nz) && (t & 63) == 0) atomicOr(&anyv, 1);
    __syncthreads();
    if (t == 0) flags[mb] = (unsigned char)anyv;
  }
}

// ---------------- GEMM (BMx128, BK=64, XOR-swizzle, 2-phase dbuf, COUNTED vmcnt) ----------------
// T4: raw barriers, never drain vmcnt to 0 mid-loop. Per iter: GSTAGE(next) -> wait
// vmcnt(NLOADS) (previous tile's loads done; the NLOADS just issued stay in flight) ->
// barrier -> compute(cur) -> lgkmcnt(0) -> barrier. The buffer overwritten by GSTAGE
// was last read an iteration ago (fenced by that iter's lgkm-barrier).
template <int MODE, int BM>
__global__ __launch_bounds__(256, BM == 64 ? 3 : 2)
void k_gemm(const unsigned short* __restrict__ A,
            const unsigned short* __restrict__ Bt,
            const float* __restrict__ bias0,
            const float* __restrict__ bias1,
            const float* __restrict__ bias2,
            unsigned short* __restrict__ q_ws,
            unsigned short* __restrict__ k_ws,
            unsigned short* __restrict__ vt_ws,
            float* __restrict__ outp) {
  constexpr int MR = BM / 32;             // M-frags per wave (wave covers BM/2 rows)
  constexpr int ACH = BM * 8 / 256;       // A staging chunks
  constexpr int NLOADS = ACH + 4;         // gload_lds per GSTAGE per thread
  const int bn = blockIdx.x, bm = blockIdx.y;
  const int t = threadIdx.x;
  const int lane = t & 63, li = lane & 15, g = lane >> 4;
  const int wid = t >> 6, wr = wid >> 1, wc = wid & 1;
  __shared__ unsigned short lds_a[2][BM * 64];    // [buf][row][slot], slot s = G col s^(row&7)
  __shared__ unsigned short lds_b[2][128 * 64];

  const f32x4 z = {0.f, 0.f, 0.f, 0.f};
  f32x4 acc[MR][4];
#pragma unroll
  for (int m = 0; m < MR; ++m)
#pragma unroll
    for (int n = 0; n < 4; ++n) acc[m][n] = z;

  const unsigned short* asrc[ACH];
  const unsigned short* bsrc[4];
  int adst[ACH], bdst[4];
#pragma unroll
  for (int c = 0; c < ACH; ++c) {
    const int idx = c * 256 + t, row = idx >> 3, sl = idx & 7;
    asrc[c] = A + (size_t)(bm * BM + row) * 1024 + ((sl ^ (row & 7)) * 8);
    adst[c] = idx * 8;
  }
#pragma unroll
  for (int c = 0; c < 4; ++c) {
    const int idx = c * 256 + t, row = idx >> 3, sl = idx & 7;
    bsrc[c] = Bt + (size_t)(bn * 128 + row) * 1024 + ((sl ^ (row & 7)) * 8);
    bdst[c] = idx * 8;
  }
  const int rs = li & 7;

#define GSTAGE(buf, kc)                                                  \
  {                                                                      \
    _Pragma("unroll")                                                    \
    for (int c = 0; c < ACH; ++c) gload_lds16(asrc[c] + (kc), &lds_a[buf][adst[c]]); \
    _Pragma("unroll")                                                    \
    for (int c = 0; c < 4; ++c)   gload_lds16(bsrc[c] + (kc), &lds_b[buf][bdst[c]]); \
  }

  GSTAGE(0, 0);                           // prologue loads in flight (no drain)

#pragma unroll 1
  for (int it = 0; it < 16; ++it) {
    const int cur = it & 1;
    if (it + 1 < 16) {
      GSTAGE(cur ^ 1, (it + 1) * 64);     // issue next tile first
      waitcnt_vm<NLOADS>();               // cur's loads done; next's stay in flight
    } else {
      waitcnt_vm<0>();                    // last tile: drain all
    }
    __builtin_amdgcn_s_barrier();         // cur readable by all waves
    __builtin_amdgcn_sched_barrier(0);
#pragma unroll
    for (int ks = 0; ks < 2; ++ks) {
      short8 af[MR], bf[4];
#pragma unroll
      for (int m = 0; m < MR; ++m)
        af[m] = *(const short8*)&lds_a[cur][(wr * (BM / 2) + m * 16 + li) * 64 +
                                            (((ks * 4 + g) ^ rs) * 8)];
#pragma unroll
      for (int n = 0; n < 4; ++n)
        bf[n] = *(const short8*)&lds_b[cur][(wc * 64 + n * 16 + li) * 64 +
                                            (((ks * 4 + g) ^ rs) * 8)];
#pragma unroll
      for (int m = 0; m < MR; ++m)
#pragma unroll
        for (int n = 0; n < 4; ++n)
          acc[m][n] = MFMA(af[m], bf[n], acc[m][n], 0, 0, 0);
    }
    asm volatile("s_waitcnt lgkmcnt(0)" ::: "memory");   // my reads of cur done
    __builtin_amdgcn_s_barrier();                        // everyone's reads done
    __builtin_amdgcn_sched_barrier(0);
  }
#undef GSTAGE

#pragma unroll
  for (int m = 0; m < MR; ++m) {
    const int row0 = bm * BM + wr * (BM / 2) + m * 16 + 4 * g;
#pragma unroll
    for (int n = 0; n < 4; ++n) {
      const int col = bn * 128 + wc * 64 + n * 16 + li;
      f32x4 v = acc[m][n];
      if (MODE == 1) {
        const float bias = bias0[col];
#pragma unroll
        for (int r = 0; r < 4; ++r) outp[(size_t)(row0 + r) * 1024 + col] = v[r] + bias;
      } else {
        if (col < 1024) {
          const float bias = bias0[col];
#pragma unroll
          for (int r = 0; r < 4; ++r) q_ws[(size_t)(row0 + r) * 1024 + col] = f2bf((v[r] + bias) * QSC);
        } else if (col < 1280) {
          const int cc = col - 1024;
          const float bias = bias1[cc];
#pragma unroll
          for (int r = 0; r < 4; ++r) k_ws[(size_t)(row0 + r) * 256 + cc] = f2bf(v[r] + bias);
        } else {
          const int cc = col - 1280;
          const float bias = bias2[cc];
          const int kvh = cc >> 6, d = cc & 63;
          const int b = row0 >> 11, l0 = row0 & 2047;
          u16x4 pk = { f2bf(v[0] + bias), f2bf(v[1] + bias), f2bf(v[2] + bias), f2bf(v[3] + bias) };
          *(u16x4*)(vt_ws + ((size_t)((b * KVH_ + kvh) * 64 + d)) * 2048 + l0) = pk;
        }
      }
    }
  }
}

// ---------------- flash attention (GQA, 8 waves: (kj-half, head), 32x32 MFMA, reg-P) ----------------
// Frozen R9 configuration (best measured: 48.4 us, VGPR 64, zero spill).
__global__ __launch_bounds__(512, 4) void k_attn(const unsigned short* __restrict__ q_ws,
                                                 const unsigned short* __restrict__ k_ws,
                                                 const unsigned short* __restrict__ vt_ws,
                                                 const float* __restrict__ mask,
                                                 const unsigned char* __restrict__ mflags,
                                                 unsigned short* __restrict__ ctx) {
  const int bk = blockIdx.x;            // b*4 + kvh (== XCD id -> L2 locality)
  const int qt = blockIdx.y;            // 32-row q tile
  const int b = bk >> 2, kvh = bk & 3;
  const int t = threadIdx.x;            // 0..511
  const int wid = t >> 6, lane = t & 63;
  const int l31 = lane & 31, g1 = lane >> 5;
  const int h = wid & 3, kh = wid >> 2;

  __shared__ unsigned short smem[16384];   // 32KB: 2 bufs x [K 8KB | V 8KB]
  __shared__ float lred[4][64];            // [h][lane] l partials from kh=1

  const unsigned short* qbase = q_ws + ((size_t)b * L_ + qt * 32 + l31) * H_ +
                                (kvh * 4 + h) * 64 + g1 * 8;
  short8 qf[4];
#pragma unroll
  for (int ks = 0; ks < 4; ++ks) qf[ks] = *(const short8*)(qbase + ks * 16);

  const unsigned int* fp = (const unsigned int*)(mflags + b * 1024 + (qt >> 1) * 32);
  unsigned int fm = 0;
#pragma unroll
  for (int w = 0; w < 8; ++w) {
    unsigned int wv = fp[w];
    fm |= ((wv & 0x000000FFu) ? 1u : 0u) << (w * 4 + 0);
    fm |= ((wv & 0x0000FF00u) ? 1u : 0u) << (w * 4 + 1);
    fm |= ((wv & 0x00FF0000u) ? 1u : 0u) << (w * 4 + 2);
    fm |= ((wv & 0xFF000000u) ? 1u : 0u) << (w * 4 + 3);
  }
  fm = __builtin_amdgcn_readfirstlane(fm);

  const int srow = t >> 3, sgr = t & 7;
  const int swz = (sgr ^ (srow & 7)) * 8;
  const unsigned short* ksrc = k_ws + ((size_t)b * L_ + srow) * 256 + kvh * 64 + swz;
  const unsigned short* vsrc = vt_ws + ((size_t)(b * KVH_ + kvh) * 64 + srow) * 2048 + swz;

  const f32x16 z16 = {0,0,0,0,0,0,0,0,0,0,0,0,0,0,0,0};
  f32x16 o_[2];
  o_[0] = z16; o_[1] = z16;
  float l_part = 0.f;

  const int rK = kh * 32 + l31, swK = rK & 7;
  const int swV = l31 & 7;

  short8 kst, vst;
#define LOADR(kt) { kst = *(const short8*)(ksrc + (size_t)(kt) * 16384); \
                    vst = *(const short8*)(vsrc + (kt) * 64); }
#define WRITES(buf) { unsigned short* dk = smem + (buf) * 8192;          \
                      *(short8*)(dk + t * 8) = kst;                      \
                      *(short8*)(dk + 4096 + t * 8) = vst; }

  LOADR(0);
  WRITES(0);
  LOADR(1);
  __syncthreads();

#pragma unroll 1
  for (int kt = 0; kt < 32; ++kt) {
    const int cur = kt & 1;
    const unsigned short* lk = smem + cur * 8192;
    const unsigned short* lv = lk + 4096;

    short8 kf[4];
#pragma unroll
    for (int ks = 0; ks < 4; ++ks)
      kf[ks] = *(const short8*)&lk[rK * 64 + ((ks * 2 + g1) ^ swK) * 8];
    short8 vf[2][2];
#pragma unroll
    for (int db = 0; db < 2; ++db)
#pragma unroll
      for (int s = 0; s < 2; ++s)
        vf[db][s] = *(const short8*)&lv[(db * 32 + l31) * 64 + ((kh * 4 + s * 2 + g1) ^ swV) * 8];

    asm volatile("s_waitcnt vmcnt(0)" ::: "memory");
    if (kt + 1 < 32) WRITES(cur ^ 1);
    if (kt + 2 < 32) LOADR(kt + 2);

    f32x16 sv = z16;
    __builtin_amdgcn_s_setprio(1);
#pragma unroll
    for (int ks = 0; ks < 4; ++ks) sv = MFMA32(kf[ks], qf[ks], sv, 0, 0, 0);
    __builtin_amdgcn_s_setprio(0);

    if (fm & (1u << kt)) {
      const float* mrow = mask + ((size_t)b * L_ + qt * 32 + l31) * L_ + kt * 64 + kh * 32 + g1 * 4;
#pragma unroll
      for (int rg = 0; rg < 4; ++rg) {
        float4 mv = *(const float4*)(mrow + rg * 8);
#pragma unroll
        for (int j = 0; j < 4; ++j) sv[rg * 4 + j] = fmaf((&mv.x)[j], LOG2E, sv[rg * 4 + j]);
      }
    }

    float e[16];
#pragma unroll
    for (int r = 0; r < 16; ++r) e[r] = EXP2(sv[r]);
    l_part += (((e[0] + e[1]) + (e[2] + e[3])) + ((e[4] + e[5]) + (e[6] + e[7]))) +
              (((e[8] + e[9]) + (e[10] + e[11])) + ((e[12] + e[13]) + (e[14] + e[15])));
    unsigned int w0 = cvtpk(e[0], e[1]),   w1 = cvtpk(e[2], e[3]);
    unsigned int w2 = cvtpk(e[4], e[5]),   w3 = cvtpk(e[6], e[7]);
    unsigned int w4 = cvtpk(e[8], e[9]),   w5 = cvtpk(e[10], e[11]);
    unsigned int w6 = cvtpk(e[12], e[13]), w7 = cvtpk(e[14], e[15]);
    plswap(w0, w2); plswap(w1, w3);
    plswap(w4, w6); plswap(w5, w7);
    short8 pa0 = mk8(w0, w1, w2, w3);
    short8 pa1 = mk8(w4, w5, w6, w7);

    __builtin_amdgcn_s_setprio(1);
#pragma unroll
    for (int db = 0; db < 2; ++db) {
      o_[db] = MFMA32(vf[db][0], pa0, o_[db], 0, 0, 0);
      o_[db] = MFMA32(vf[db][1], pa1, o_[db], 0, 0, 0);
    }
    __builtin_amdgcn_s_setprio(0);

    asm volatile("s_waitcnt lgkmcnt(0)" ::: "memory");
    __builtin_amdgcn_s_barrier();
    __builtin_amdgcn_sched_barrier(0);
  }
#undef LOADR
#undef WRITES

  float lt = l_part + __shfl_xor(l_part, 32);
  float* red = (float*)smem;

  if (kh == 1) {
    lred[h][lane] = lt;
#pragma unroll
    for (int db = 0; db < 2; ++db)
#pragma unroll
      for (int w4 = 0; w4 < 4; ++w4) {
        f32x4 pv = { o_[db][w4 * 4 + 0], o_[db][w4 * 4 + 1],
                     o_[db][w4 * 4 + 2], o_[db][w4 * 4 + 3] };
        *(f32x4*)&red[(((h * 2 + db) * 4 + w4) * 64 + lane) * 4] = pv;
      }
  }
  __syncthreads();

  if (kh == 0) {
    const float inv = 1.f / (lt + lred[h][lane]);
#pragma unroll
    for (int db = 0; db < 2; ++db) {
      f32x16 acc = o_[db];
#pragma unroll
      for (int w4 = 0; w4 < 4; ++w4) {
        f32x4 pv = *(const f32x4*)&red[(((h * 2 + db) * 4 + w4) * 64 + lane) * 4];
#pragma unroll
        for (int j = 0; j < 4; ++j) acc[w4 * 4 + j] += pv[j];
      }
      unsigned short* cp = ctx + ((size_t)b * L_ + qt * 32 + l31) * H_ +
                           (kvh * 4 + h) * 64 + db * 32 + g1 * 4;
#pragma unroll
      for (int k4 = 0; k4 < 4; ++k4) {
        unsigned int a0 = cvtpk(acc[4 * k4 + 0] * inv, acc[4 * k4 + 1] * inv);
        unsigned int a1 = cvtpk(acc[4 * k4 + 2] * inv, acc[4 * k4 + 3] * inv);
        *(unsigned int*)(cp + 8 * k4) = a0;
        *(unsigned int*)(cp + 8 * k4 + 2) = a1;
      }
    }
  }
}

// ---------------- launch ----------------
extern "C" void kernel_launch(void* const* d_in, const int* in_sizes, int n_in,
                              void* d_out, int out_size, void* d_ws, size_t ws_size,
                              hipStream_t stream) {
  const float* x    = (const float*)d_in[0];
  const float* mask = (const float*)d_in[1];
  const float* Wq   = (const float*)d_in[2];
  const float* bq   = (const float*)d_in[3];
  const float* Wk   = (const float*)d_in[4];
  const float* bk   = (const float*)d_in[5];
  const float* Wv   = (const float*)d_in[6];
  const float* bv   = (const float*)d_in[7];
  const float* Wo   = (const float*)d_in[8];
  const float* bo   = (const float*)d_in[9];
  float* out = (float*)d_out;

  char* ws = (char*)d_ws;
  unsigned short* xb    = (unsigned short*)(ws);                 // 8 MB (reused as ctx)
  unsigned short* ctx   = xb;
  unsigned short* wcat  = (unsigned short*)(ws + 8388608);       // 3 MB
  unsigned short* wo_b  = (unsigned short*)(ws + 11534336);      // 2 MB
  unsigned short* q_ws  = (unsigned short*)(ws + 13631488);      // 8 MB
  unsigned short* k_ws  = (unsigned short*)(ws + 22020096);      // 2 MB
  unsigned short* vt_ws = (unsigned short*)(ws + 24117248);      // 2 MB
  unsigned char*  mflg  = (unsigned char*)(ws + 26214400);       // 2 KB

  k_prep<<<dim3(8704), dim3(256), 0, stream>>>(x, Wq, Wk, Wv, Wo, mask, xb, wcat, wo_b, mflg);
  k_gemm<0, 64><<<dim3(12, 64), dim3(256), 0, stream>>>(xb, wcat, bq, bk, bv, q_ws, k_ws, vt_ws, nullptr);
  k_attn<<<dim3(8, 64), dim3(512), 0, stream>>>(q_ws, k_ws, vt_ws, mask, mflg, ctx);
  k_gemm<1, 128><<<dim3(8, 32), dim3(256), 0, stream>>>(ctx, wo_b, bo, nullptr, nullptr,
                                                        nullptr, nullptr, nullptr, out);
}